// Round 10
// baseline (106.096 us; speedup 1.0000x reference)
//
#include <hip/hip_runtime.h>
#include <hip/hip_bf16.h>

typedef int   i32x4 __attribute__((ext_vector_type(4)));

#define N_IMG 64
#define CIN   256
#define COUT  256
#define HH    28
#define WW    28
#define PH    30
#define PW    30
#define M_TOT (N_IMG*HH*WW)          // 50176
#define OUT_ELEMS (N_IMG*COUT*HH*WW) // 12845056

// workspace layout (bytes) — all int8
#define XT_BYTES   ((size_t)N_IMG*PH*PW*CIN)       // 14745600
#define WT_OFF     (XT_BYTES)
#define WT_BYTES   ((size_t)9*COUT*CIN)            // 589824
#define BQ_OFF     (WT_OFF + WT_BYTES)             // 15335424

#define GLD16(g, l) __builtin_amdgcn_global_load_lds( \
    (const __attribute__((address_space(1))) void*)(g), \
    (__attribute__((address_space(3))) void*)(l), 16, 0, 0)

// ---------------------------------------------------------------------------
// Kernel 1: x int32 NCHW -> padded int8 NHWC [N][30][30][256], value x-127,
// PAD = -127  (so conv_i8 + 127*sum(w) == true conv with zero-padding).
__global__ __launch_bounds__(256) void transform_x(const int* __restrict__ xq,
                                                   signed char* __restrict__ xt) {
    __shared__ int xs[CIN*29];     // padded stride 29 -> no bank conflicts
    const int b = blockIdx.x;
    const int n = b / PH, py = b % PH;
    const int t = threadIdx.x;
    signed char* dst = xt + ((size_t)(n*PH + py))*PW*CIN;
    if (py == 0 || py == PH-1) {
        for (int i = t; i < PW*CIN; i += 256) dst[i] = -127;
        return;
    }
    const int h = py - 1;
    const int* src = xq + (size_t)n*CIN*HH*WW + h*WW;
    for (int i = t; i < CIN*WW; i += 256) {
        const int ci = i / WW, w = i % WW;
        xs[ci*29 + w] = src[ci*HH*WW + w];
    }
    __syncthreads();
    for (int i = t; i < PW*CIN; i += 256) {
        const int px = i / CIN, ci = i % CIN;
        const int v = (px == 0 || px == PW-1) ? 0 : xs[ci*29 + (px-1)];
        dst[px*CIN + ci] = (signed char)(v - 127);
    }
}

// ---------------------------------------------------------------------------
// Kernel 2: per-channel weight quant (int8) + bias quant + scale_out.
// wt layout: [tap(9)][co(256)][ci(256)] int8.  bq[co] folds in the +127*S
// correction for the x-shift (S = sum of all w_q for channel co).
__global__ __launch_bounds__(256) void quant_w(const float* __restrict__ weight,
                                               const float* __restrict__ scale_x,
                                               const float* __restrict__ bias,
                                               signed char* __restrict__ wt,
                                               int* __restrict__ bq,
                                               float* __restrict__ out_tail) {
    __shared__ float red[256];
    __shared__ int  sred[256];
    const int co = blockIdx.x, t = threadIdx.x;
    const float* wrow = weight + (size_t)co*CIN*9;
    float wv[9];
    float mx = 0.f;
    for (int it = 0; it < 9; ++it) {
        float v = wrow[it*256 + t];
        wv[it] = v;
        mx = fmaxf(mx, fabsf(v));
    }
    red[t] = mx;
    __syncthreads();
    for (int s = 128; s > 0; s >>= 1) {
        if (t < s) red[t] = fmaxf(red[t], red[t+s]);
        __syncthreads();
    }
    const float scale = fmaxf(red[0], 1e-8f) / 127.f;
    int isum = 0;
    for (int it = 0; it < 9; ++it) {
        const int i = it*256 + t;          // index over [ci][r][s]
        const int ci = i / 9, rs = i % 9;
        float q = rintf(wv[it] / scale);   // rintf = round-half-even = jnp.round
        q = fminf(fmaxf(q, -128.f), 127.f);
        const int qi = (int)q;
        isum += qi;
        wt[(size_t)rs*COUT*CIN + co*CIN + ci] = (signed char)qi;
    }
    sred[t] = isum;
    __syncthreads();
    for (int s = 128; s > 0; s >>= 1) {
        if (t < s) sred[t] += sred[t+s];
        __syncthreads();
    }
    if (t == 0) {
        const float so = scale * scale_x[0];
        out_tail[co] = so;
        bq[co] = (int)rintf(bias[co] / so) + 127 * sred[0];
    }
}

// ---------------------------------------------------------------------------
// Kernel 3: implicit-GEMM conv, int8 MFMA (mfma_i32_16x16x64_i8, exact i32).
// BM=256 (all co) x BN=128 x BK=64, 512 thr / 8 waves (4 co x 2 m), per-wave
// 64x64 = acc[4][4], 16 MFMA + 8 ds_read_b128 per K-tile per wave.
// 36 K-tiles.  LDS: THREE buffers x (A 16KB + B 8KB) = 72KB -> still 2
// blocks/CU (m114 inter-block overlap).  Pipeline depth 2: STAGE(t+2) each
// iter; gate at top of iter t is s_waitcnt vmcnt(3) = "tile t's 3 loads
// (issued 2 phases ago) retired; tile t+1's still in flight" — never drains
// to 0 in the main loop (T4).
__global__ __launch_bounds__(512, 4) void conv_mfma(const signed char* __restrict__ xt,
                                                    const signed char* __restrict__ wt,
                                                    const int* __restrict__ bq,
                                                    float* __restrict__ out) {
    __shared__ signed char Ash[3*16384];  // [buf][kc4][row256][16]
    __shared__ signed char Bsh[3*8192];   // [buf][kc4][row128][16]
    const int d = threadIdx.x;
    const int w8 = d >> 6;                   // wave id 0..7
    const int lane = d & 63, lr = lane & 15, kg = lane >> 4;
    const int wm = w8 >> 1, wn = w8 & 1;     // wave grid: 4 (co) x 2 (m)
    const int m0 = blockIdx.x << 7;          // BN=128

    // staging: A thread d -> row d&255, kc (d>>8) and (d>>8)+2 (2 loads)
    //          B thread d -> row d&127, kc (d>>7)            (1 load)
    const signed char* aS = wt + (d & 255)*CIN + ((d >> 8) << 4);
    const signed char* bS;
    {
        const int m = m0 + (d & 127);
        const int n = m / 784, hw = m % 784, h = hw / 28, wq = hw % 28;
        bS = xt + ((size_t)((n*PH + h)*PW + wq))*CIN + ((d >> 7) << 4);
    }
    const int dstw = w8 << 10;               // wave-uniform LDS byte base

    i32x4 acc[4][4] = {};

    // frag read byte bases: A: kg*4096 + row*16 ; B: kg*2048 + row*16
    const int arb = kg*4096 + (wm*64 + lr)*16;
    const int brb = kg*2048 + (wn*64 + lr)*16;

#define STAGE(T_, P_) do { \
    const int tap_ = (T_) >> 2, c_ = (T_) & 3; \
    const int r3_ = (tap_*171) >> 9; \
    const int ao_ = tap_*(COUT*CIN) + (c_ << 6); \
    const int bo_ = ((r3_*PW + (tap_ - r3_*3)) << 8) + (c_ << 6); \
    GLD16(aS + ao_,      Ash + (P_)*16384 + dstw); \
    GLD16(aS + ao_ + 32, Ash + (P_)*16384 + 8192 + dstw); \
    GLD16(bS + bo_,      Bsh + (P_)*8192 + dstw); \
} while (0)

#define COMPUTE(P_) do { \
    const signed char* A_ = Ash + (P_)*16384; \
    const signed char* B_ = Bsh + (P_)*8192; \
    i32x4 af[4], bf[4]; \
    _Pragma("unroll") \
    for (int mr = 0; mr < 4; ++mr) af[mr] = *(const i32x4*)&A_[arb + mr*256]; \
    _Pragma("unroll") \
    for (int nr = 0; nr < 4; ++nr) bf[nr] = *(const i32x4*)&B_[brb + nr*256]; \
    _Pragma("unroll") \
    for (int mr = 0; mr < 4; ++mr) \
        _Pragma("unroll") \
        for (int nr = 0; nr < 4; ++nr) \
            acc[mr][nr] = __builtin_amdgcn_mfma_i32_16x16x64_i8( \
                af[mr], bf[nr], acc[mr][nr], 0, 0, 0); \
} while (0)

// gate: wait tile-to-compute's loads (issued 2 phases ago); keep next tile's
// 3 loads in flight.  barrier makes it block-wide; sched_barrier pins order.
#define GATE(N_) do { \
    asm volatile("s_waitcnt vmcnt(" #N_ ")" ::: "memory"); \
    __builtin_amdgcn_s_barrier(); \
    __builtin_amdgcn_sched_barrier(0); \
} while (0)

    STAGE(0, 0);
    STAGE(1, 1);
#pragma unroll 1
    for (int tt = 0; tt < 33; tt += 3) {     // tiles 0..32, staging up to 34
        GATE(3); STAGE(tt + 2, 2); COMPUTE(0);
        GATE(3); STAGE(tt + 3, 0); COMPUTE(1);
        GATE(3); STAGE(tt + 4, 1); COMPUTE(2);
    }
    GATE(3); STAGE(35, 2); COMPUTE(0);       // tile 33
    GATE(3); COMPUTE(1);                     // tile 34 (35's loads in flight)
    GATE(0); COMPUTE(2);                     // tile 35

    // epilogue: D row = co (kg*4+rg), col = m (lr); 64B coalesced runs
#pragma unroll
    for (int nr = 0; nr < 4; ++nr) {
        const int mm = m0 + wn*64 + nr*16 + lr;
        const int nn = mm / 784, hw2 = mm % 784;
        float* orow = out + (size_t)nn*COUT*784 + hw2;
#pragma unroll
        for (int mr = 0; mr < 4; ++mr) {
            const int co = wm*64 + mr*16 + kg*4;
#pragma unroll
            for (int rg = 0; rg < 4; ++rg)
                orow[(size_t)(co + rg)*784] = (float)(acc[mr][nr][rg] + bq[co + rg]);
        }
    }
#undef STAGE
#undef COMPUTE
#undef GATE
}

// ---------------------------------------------------------------------------
extern "C" void kernel_launch(void* const* d_in, const int* in_sizes, int n_in,
                              void* d_out, int out_size, void* d_ws, size_t ws_size,
                              hipStream_t stream) {
    const int*   xq      = (const int*)d_in[0];
    const float* scale_x = (const float*)d_in[1];
    const float* weight  = (const float*)d_in[2];
    const float* bias    = (const float*)d_in[3];
    float* out = (float*)d_out;

    signed char* xt = (signed char*)d_ws;
    signed char* wt = (signed char*)((char*)d_ws + WT_OFF);
    int*         bq = (int*)((char*)d_ws + BQ_OFF);

    hipLaunchKernelGGL(transform_x, dim3(N_IMG*PH), dim3(256), 0, stream, xq, xt);
    hipLaunchKernelGGL(quant_w, dim3(COUT), dim3(256), 0, stream,
                       weight, scale_x, bias, wt, bq, out + OUT_ELEMS);
    hipLaunchKernelGGL(conv_mfma, dim3(M_TOT/128), dim3(512), 0, stream,
                       xt, wt, bq, out);
}